// Round 11
// baseline (276.598 us; speedup 1.0000x reference)
//
#include <hip/hip_runtime.h>
#include <cstddef>

#define SS 1024
#define DF 768
#define NBATCH 16
#define GAT_ALPHA 0.2f

typedef _Float16 f16x8 __attribute__((ext_vector_type(8)));
typedef _Float16 f16x4 __attribute__((ext_vector_type(4)));
typedef float f32x4 __attribute__((ext_vector_type(4)));

// async global->LDS, 16B per lane. LDS dest is wave-uniform base + lane*16.
__device__ __forceinline__ void gload16(const void* g, void* l) {
  __builtin_amdgcn_global_load_lds(
      (const __attribute__((address_space(1))) void*)g,
      (__attribute__((address_space(3))) void*)l, 16, 0, 0);
}

__device__ __forceinline__ float lrelu(float t) {
  return fmaxf(t, GAT_ALPHA * t);
}

// ---------------------------------------------------------------------------
// fp32 -> fp16 convert, 4 elems/thread
// ---------------------------------------------------------------------------
__global__ __launch_bounds__(256) void f32tof16_k(const float* __restrict__ in,
                                                  _Float16* __restrict__ out,
                                                  int n) {
  int idx = (blockIdx.x * 256 + threadIdx.x) * 4;
  if (idx + 3 < n) {
    float4 v = *(const float4*)&in[idx];
    f16x4 o;
    o[0] = (_Float16)v.x;
    o[1] = (_Float16)v.y;
    o[2] = (_Float16)v.z;
    o[3] = (_Float16)v.w;
    *(f16x4*)&out[idx] = o;
  }
}

// ---------------------------------------------------------------------------
// pack: int32 mask (64MB) -> bitmask (2MB). byte t holds j=8t..8t+7 (bit k).
// ---------------------------------------------------------------------------
__global__ __launch_bounds__(256) void pack_k(const int* __restrict__ mask,
                                              unsigned char* __restrict__ bm) {
  const size_t t = (size_t)blockIdx.x * 256 + threadIdx.x;  // byte idx, 2M
  const int* mp = mask + t * 8;
  const int4 a = *(const int4*)mp;
  const int4 c = *(const int4*)(mp + 4);
  unsigned v = (unsigned)(a.x > 0) | ((unsigned)(a.y > 0) << 1) |
               ((unsigned)(a.z > 0) << 2) | ((unsigned)(a.w > 0) << 3) |
               ((unsigned)(c.x > 0) << 4) | ((unsigned)(c.y > 0) << 5) |
               ((unsigned)(c.z > 0) << 6) | ((unsigned)(c.w > 0) << 7);
  bm[t] = (unsigned char)v;
}

// ===========================================================================
// GEMM core v11: 256 threads, 4 waves (2x2), BM=BN=128, BK=32, 4-slot 64KB
// LDS ring, depth-2 prefetch, counted vmcnt(4), ONE barrier per K-tile:
//   { ds_read frags(t); stage(t+2); vmcnt(4); barrier; 16 MFMA }
// 2 blocks/CU (launch_bounds(256,2)) so barrier/vmcnt waits of one block
// overlap compute of the other. XOR chunk swizzle both-sides; XCD swizzle.
// Hazards: reads t vs writes t+2 disjoint; t+2's prior readers done 2
// barriers ago; per-wave vmcnt(4)+barrier => slot t+1 landed for all waves.
// ===========================================================================

// ---------------------------------------------------------------------------
// GEMM1: hT16[b][n][s] = f16( sum_k X16[m,k]*W16[n,k] + Wb[n] ), m=b*1024+s
// Epilogue: per-wave LDS transpose (64x64, pad 72) -> coalesced hT write +
// fused rowdots partials psi6/psj6[nt][m] (nt = n-tile 0..5).
// ---------------------------------------------------------------------------
__global__ __launch_bounds__(256, 2) void gemm1_k(
    const _Float16* __restrict__ X16, const _Float16* __restrict__ W16,
    const float* __restrict__ Wbl, const float* __restrict__ Al,
    _Float16* __restrict__ hT16, float* __restrict__ psi6,
    float* __restrict__ psj6) {
  // loop: 4 slots x 16KB = 64KB; epilogue reuses: tb 4x9216 + av 1KB + pw 2KB
  __shared__ __align__(16) char smem[65536];
  const int flat = blockIdx.x + 128 * blockIdx.y;  // grid (128,6) = 768
  const int swz = (flat & 7) * 96 + (flat >> 3);   // XCD-chunked (768%8==0)
  const int m0 = (swz & 127) * 128;
  const int nt = swz >> 7;  // 0..5
  const int n0 = nt * 128;
  const int tid = threadIdx.x;
  const int w = tid >> 6, lane = tid & 63;
  const int wr = w >> 1, wc = w & 1;

  const int sk8 = ((tid & 3) ^ ((tid >> 3) & 3)) * 8;      // swizzled src
  const int rby = ((lane >> 4) ^ ((lane >> 1) & 3)) * 16;  // swizzled read
  const int rrow = lane & 15;

  f32x4 acc[4][4];
#pragma unroll
  for (int mi = 0; mi < 4; ++mi)
#pragma unroll
    for (int ni = 0; ni < 4; ++ni) acc[mi][ni] = (f32x4)(0.f);

#define STG1(s, kt)                                                     \
  {                                                                     \
    _Pragma("unroll") for (int q = 0; q < 2; ++q) {                     \
      const int row = q * 64 + (tid >> 2);                              \
      gload16(&X16[(size_t)(m0 + row) * DF + (kt) * 32 + sk8],          \
              smem + (s) * 16384 + q * 4096 + w * 1024);                \
      gload16(&W16[(size_t)(n0 + row) * DF + (kt) * 32 + sk8],          \
              smem + (s) * 16384 + 8192 + q * 4096 + w * 1024);         \
    }                                                                   \
  }

  const int NT = DF / 32;  // 24
  STG1(0, 0);
  STG1(1, 1);
  asm volatile("s_waitcnt vmcnt(4)" ::: "memory");
  asm volatile("s_barrier" ::: "memory");

  for (int t = 0; t < NT; ++t) {
    const char* Ab = smem + (t & 3) * 16384;
    const char* Bb = Ab + 8192;
    f16x8 afr[4], bfr[4];
#pragma unroll
    for (int mi = 0; mi < 4; ++mi)
      afr[mi] = *(const f16x8*)(Ab + (wr * 64 + mi * 16 + rrow) * 64 + rby);
#pragma unroll
    for (int ni = 0; ni < 4; ++ni)
      bfr[ni] = *(const f16x8*)(Bb + (wc * 64 + ni * 16 + rrow) * 64 + rby);
    if (t + 2 < NT) STG1((t + 2) & 3, t + 2);
    if (t < NT - 2)
      asm volatile("s_waitcnt vmcnt(4)" ::: "memory");
    else
      asm volatile("s_waitcnt vmcnt(0)" ::: "memory");
    asm volatile("s_barrier" ::: "memory");
    __builtin_amdgcn_s_setprio(1);
#pragma unroll
    for (int mi = 0; mi < 4; ++mi)
#pragma unroll
      for (int ni = 0; ni < 4; ++ni)
        acc[mi][ni] = __builtin_amdgcn_mfma_f32_16x16x32_f16(
            afr[mi], bfr[ni], acc[mi][ni], 0, 0, 0);
    __builtin_amdgcn_s_setprio(0);
  }
#undef STG1

  // ---- epilogue: transpose + fused rowdots + coalesced hT write ----
  __syncthreads();
  float* asrc = (float*)(smem + 36864);  // 128 f32
  float* adst = asrc + 128;
  float* pwsi = (float*)(smem + 37888);  // [128][2]
  float* pwsj = pwsi + 256;
  if (tid < 128) {
    asrc[tid] = Al[n0 + tid];
    adst[tid] = Al[DF + n0 + tid];
  }
  _Float16* tb = (_Float16*)smem + w * 4608;  // 64 cols x 72 (pad)
  const int cg = lane >> 4, cr = lane & 15;
  float bias[4];
#pragma unroll
  for (int ni = 0; ni < 4; ++ni) bias[ni] = Wbl[n0 + wc * 64 + ni * 16 + cr];
#pragma unroll
  for (int mi = 0; mi < 4; ++mi) {
#pragma unroll
    for (int ni = 0; ni < 4; ++ni) {
      f16x4 tv;
#pragma unroll
      for (int r = 0; r < 4; ++r)
        tv[r] = (_Float16)(acc[mi][ni][r] + bias[ni]);
      *(f16x4*)&tb[(ni * 16 + cr) * 72 + mi * 16 + cg * 4] = tv;
    }
  }
  __syncthreads();
  // rowdots: lane = wave-local row (0..63); sum over wave's 64 cols
  {
    float ps = 0.f, pd = 0.f;
    const float* wa = asrc + wc * 64;
    const float* wd = adst + wc * 64;
#pragma unroll 8
    for (int c = 0; c < 64; ++c) {
      const float hv = (float)tb[c * 72 + lane];
      ps = fmaf(hv, wa[c], ps);
      pd = fmaf(hv, wd[c], pd);
    }
    pwsi[(wr * 64 + lane) * 2 + wc] = ps;
    pwsj[(wr * 64 + lane) * 2 + wc] = pd;
  }
  // coalesced hT write: 128B contiguous per col
  const int bb = m0 >> 10;
  const int s0w = (m0 & 1023) + wr * 64;
#pragma unroll
  for (int pass = 0; pass < 8; ++pass) {
    const int cl = pass * 8 + (lane >> 3);
    f16x8 v = *(const f16x8*)&tb[cl * 72 + (lane & 7) * 8];
    *(f16x8*)&hT16[((size_t)bb * DF + n0 + wc * 64 + cl) * SS + s0w +
                   (lane & 7) * 8] = v;
  }
  __syncthreads();
  if (tid < 128) {
    psi6[nt * 16384 + m0 + tid] = pwsi[tid * 2] + pwsi[tid * 2 + 1];
    psj6[nt * 16384 + m0 + tid] = pwsj[tid * 2] + pwsj[tid * 2 + 1];
  }
}

// ---------------------------------------------------------------------------
// GEMM2: out[b,i,d] = sum_j P16[b,i,j] * hT16[b,d,j]   (K=1024)
// ---------------------------------------------------------------------------
__global__ __launch_bounds__(256, 2) void gemm2_k(
    const _Float16* __restrict__ P16, const _Float16* __restrict__ hT16,
    float* __restrict__ outl, _Float16* __restrict__ X16n, int writeX) {
  __shared__ __align__(16) char smem[65536];  // 4 slots x 16KB
  const int flat = blockIdx.x + 8 * (blockIdx.y + 6 * blockIdx.z);  // 768
  const int swz = (flat & 7) * 96 + (flat >> 3);  // XCD gets 2 batches
  const int i0 = (swz & 7) * 128;
  const int d0 = ((swz >> 3) % 6) * 128;
  const int b = swz / 48;
  const int tid = threadIdx.x;
  const int w = tid >> 6, lane = tid & 63;
  const int wr = w >> 1, wc = w & 1;

  const int sk8 = ((tid & 3) ^ ((tid >> 3) & 3)) * 8;
  const int rby = ((lane >> 4) ^ ((lane >> 1) & 3)) * 16;
  const int rrow = lane & 15;

  const _Float16* Pb = P16 + ((size_t)b << 20);
  const _Float16* hTb = hT16 + (size_t)b * DF * SS;

  f32x4 acc[4][4];
#pragma unroll
  for (int mi = 0; mi < 4; ++mi)
#pragma unroll
    for (int ni = 0; ni < 4; ++ni) acc[mi][ni] = (f32x4)(0.f);

#define STG2(s, kt)                                                     \
  {                                                                     \
    _Pragma("unroll") for (int q = 0; q < 2; ++q) {                     \
      const int row = q * 64 + (tid >> 2);                              \
      gload16(&Pb[((size_t)(i0 + row) << 10) + (kt) * 32 + sk8],        \
              smem + (s) * 16384 + q * 4096 + w * 1024);                \
      gload16(&hTb[(size_t)(d0 + row) * SS + (kt) * 32 + sk8],          \
              smem + (s) * 16384 + 8192 + q * 4096 + w * 1024);         \
    }                                                                   \
  }

  const int NT = SS / 32;  // 32
  STG2(0, 0);
  STG2(1, 1);
  asm volatile("s_waitcnt vmcnt(4)" ::: "memory");
  asm volatile("s_barrier" ::: "memory");

  for (int t = 0; t < NT; ++t) {
    const char* Ab = smem + (t & 3) * 16384;
    const char* Bb = Ab + 8192;
    f16x8 afr[4], bfr[4];
#pragma unroll
    for (int mi = 0; mi < 4; ++mi)
      afr[mi] = *(const f16x8*)(Ab + (wr * 64 + mi * 16 + rrow) * 64 + rby);
#pragma unroll
    for (int ni = 0; ni < 4; ++ni)
      bfr[ni] = *(const f16x8*)(Bb + (wc * 64 + ni * 16 + rrow) * 64 + rby);
    if (t + 2 < NT) STG2((t + 2) & 3, t + 2);
    if (t < NT - 2)
      asm volatile("s_waitcnt vmcnt(4)" ::: "memory");
    else
      asm volatile("s_waitcnt vmcnt(0)" ::: "memory");
    asm volatile("s_barrier" ::: "memory");
    __builtin_amdgcn_s_setprio(1);
#pragma unroll
    for (int mi = 0; mi < 4; ++mi)
#pragma unroll
      for (int ni = 0; ni < 4; ++ni)
        acc[mi][ni] = __builtin_amdgcn_mfma_f32_16x16x32_f16(
            afr[mi], bfr[ni], acc[mi][ni], 0, 0, 0);
    __builtin_amdgcn_s_setprio(0);
  }
#undef STG2

  const int cg = lane >> 4, cr = lane & 15;
#pragma unroll
  for (int mi = 0; mi < 4; ++mi) {
#pragma unroll
    for (int ni = 0; ni < 4; ++ni) {
      const int d = d0 + wc * 64 + ni * 16 + cr;
      const int row0 = i0 + wr * 64 + mi * 16 + cg * 4;
#pragma unroll
      for (int r = 0; r < 4; ++r) {
        float v = acc[mi][ni][r];
        size_t o = ((size_t)b * SS + row0 + r) * DF + d;
        outl[o] = v;
        if (writeX) X16n[o] = (_Float16)v;
      }
    }
  }
}

// ---------------------------------------------------------------------------
// rowfin: combine 6 n-tile partials -> si; per-batch max(si); sjc/refj.
// ---------------------------------------------------------------------------
__global__ __launch_bounds__(256) void rowfin_k(const float* __restrict__ psi6,
                                                const float* __restrict__ psj6,
                                                const float* __restrict__ Abp,
                                                float* __restrict__ si,
                                                float* __restrict__ sjc,
                                                float* __restrict__ refj) {
  const int b = blockIdx.x;
  const int t = threadIdx.x;
  __shared__ float red[256];
  float siv[4], sjv[4];
  float mloc = -1e30f;
#pragma unroll
  for (int q = 0; q < 4; ++q) {
    const int idx = (b << 10) + t + (q << 8);
    float a = 0.f, d = 0.f;
#pragma unroll
    for (int c = 0; c < 6; ++c) {
      a += psi6[c * 16384 + idx];
      d += psj6[c * 16384 + idx];
    }
    siv[q] = a;
    sjv[q] = d;
    si[idx] = a;
    mloc = fmaxf(mloc, a);
  }
  red[t] = mloc;
  __syncthreads();
  for (int off = 128; off > 0; off >>= 1) {
    if (t < off) red[t] = fmaxf(red[t], red[t + off]);
    __syncthreads();
  }
  const float maxsi = red[0];
  const float ab = Abp[0];
#pragma unroll
  for (int q = 0; q < 4; ++q) {
    const int idx = (b << 10) + t + (q << 8);
    const float c = sjv[q] + ab;
    sjc[idx] = c;
    refj[idx] = lrelu(maxsi + c);
  }
}

// ---------------------------------------------------------------------------
// colsum: column partial sums of exp(lrelu(si+sjc)-refj) over masked i.
// ---------------------------------------------------------------------------
__global__ __launch_bounds__(256) void colsum_k(
    const unsigned char* __restrict__ bm, const float* __restrict__ si,
    const float* __restrict__ sjc, const float* __restrict__ refj,
    float* __restrict__ pden) {
  const int g = blockIdx.x;  // 0..31
  const int b = blockIdx.y;  // 0..15
  const int t = threadIdx.x;
  const int jb = t & 127;
  const int half = t >> 7;
  const int row0 = (g << 5) + (half << 4);
  __shared__ float s_si[32];
  if (t < 32) s_si[t] = si[(b << 10) + (g << 5) + t];
  __syncthreads();
  float sc[8], rf[8];
  *(float4*)&sc[0] = *(const float4*)&sjc[(b << 10) + jb * 8];
  *(float4*)&sc[4] = *(const float4*)&sjc[(b << 10) + jb * 8 + 4];
  *(float4*)&rf[0] = *(const float4*)&refj[(b << 10) + jb * 8];
  *(float4*)&rf[4] = *(const float4*)&refj[(b << 10) + jb * 8 + 4];
  float den[8] = {0.f, 0.f, 0.f, 0.f, 0.f, 0.f, 0.f, 0.f};
  const unsigned char* bp = bm + ((size_t)b << 17) + ((size_t)row0 << 7) + jb;
#pragma unroll 4
  for (int r = 0; r < 16; ++r) {
    const unsigned m = bp[(size_t)r << 7];
    const float siv = s_si[(half << 4) + r];
#pragma unroll
    for (int k = 0; k < 8; ++k) {
      if ((m >> k) & 1) den[k] += __expf(lrelu(siv + sc[k]) - rf[k]);
    }
  }
  const size_t o = ((size_t)(g * 2 + half)) * 16384 + (b << 10) + jb * 8;
  *(float4*)&pden[o] = *(float4*)&den[0];
  *(float4*)&pden[o + 4] = *(float4*)&den[4];
}

// combine 64 chunks -> rden (sentinel -1 for fully-masked column)
__global__ __launch_bounds__(256) void colcomb_k(const float* __restrict__ pden,
                                                 float* __restrict__ rden) {
  const int idx = blockIdx.x * 256 + threadIdx.x;  // b*1024 + j
  float s = 0.f;
#pragma unroll
  for (int c = 0; c < 64; ++c) s += pden[(size_t)c * 16384 + idx];
  rden[idx] = (s > 0.f) ? 1.f / s : -1.f;
}

// ---------------------------------------------------------------------------
// punorm2: P16[b][i][j] = normalized attention weight (f16), single bitmask
// pass. rden<0 sentinel => uniform column 1/S (reference's all-masked case).
// ---------------------------------------------------------------------------
__global__ __launch_bounds__(256) void punorm2_k(
    const unsigned char* __restrict__ bm, const float* __restrict__ si,
    const float* __restrict__ sjc, const float* __restrict__ refj,
    const float* __restrict__ rden, _Float16* __restrict__ P16) {
  const int g = blockIdx.x;  // 0..31
  const int b = blockIdx.y;  // 0..15
  const int t = threadIdx.x;
  const int jb = t & 127;
  const int half = t >> 7;
  const int row0 = (g << 5) + (half << 4);
  __shared__ float s_si[32];
  if (t < 32) s_si[t] = si[(b << 10) + (g << 5) + t];
  __syncthreads();
  float sc[8], rf[8], rd[8];
  *(float4*)&sc[0] = *(const float4*)&sjc[(b << 10) + jb * 8];
  *(float4*)&sc[4] = *(const float4*)&sjc[(b << 10) + jb * 8 + 4];
  *(float4*)&rf[0] = *(const float4*)&refj[(b << 10) + jb * 8];
  *(float4*)&rf[4] = *(const float4*)&refj[(b << 10) + jb * 8 + 4];
  *(float4*)&rd[0] = *(const float4*)&rden[(b << 10) + jb * 8];
  *(float4*)&rd[4] = *(const float4*)&rden[(b << 10) + jb * 8 + 4];
  const unsigned char* bp = bm + ((size_t)b << 17) + ((size_t)row0 << 7) + jb;
  _Float16* pp = P16 + ((size_t)b << 20) + ((size_t)row0 << 10) + jb * 8;
#pragma unroll 4
  for (int r = 0; r < 16; ++r) {
    const unsigned m = bp[(size_t)r << 7];
    const float siv = s_si[(half << 4) + r];
    f16x8 ph;
#pragma unroll
    for (int k = 0; k < 8; ++k) {
      float p;
      if (rd[k] < 0.f)
        p = 0.0009765625f;  // 1/1024 uniform (all-masked column)
      else if ((m >> k) & 1)
        p = __expf(lrelu(siv + sc[k]) - rf[k]) * rd[k];
      else
        p = 0.f;
      ph[k] = (_Float16)p;
    }
    *(f16x8*)(pp + ((size_t)r << 10)) = ph;
  }
}

// ---------------------------------------------------------------------------
extern "C" void kernel_launch(void* const* d_in, const int* in_sizes, int n_in,
                              void* d_out, int out_size, void* d_ws,
                              size_t ws_size, hipStream_t stream) {
  const float* X0 = (const float*)d_in[0];
  const int* mask = (const int*)d_in[1];
  const float* W = (const float*)d_in[2];
  const float* Wb = (const float*)d_in[3];
  const float* A = (const float*)d_in[4];
  const float* Ab = (const float*)d_in[5];
  float* out = (float*)d_out;

  const size_t BSD = (size_t)NBATCH * SS * DF;  // 12,582,912 elems
  const size_t BSS = (size_t)NBATCH * SS * SS;  // 16,777,216 elems
  const size_t BS = (size_t)NBATCH * SS;        // 16,384 elems

  char* p = (char*)d_ws;
  _Float16* X16 = (_Float16*)p;   p += BSD * 2;                   // 24 MB
  _Float16* hT16 = (_Float16*)p;  p += BSD * 2;                   // 24 MB
  _Float16* P16 = (_Float16*)p;   p += BSS * 2;                   // 32 MB
  _Float16* W16 = (_Float16*)p;   p += (size_t)2 * DF * DF * 2;   // 2.25 MB
  unsigned char* bmk = (unsigned char*)p; p += BSS / 8;           // 2 MB
  float* psi6 = (float*)p; p += 6 * BS * 4;   // 384 KB
  float* psj6 = (float*)p; p += 6 * BS * 4;   // 384 KB
  float* pden = (float*)p; p += 64 * BS * 4;  // 4 MB
  float* si = (float*)p;   p += BS * 4;
  float* sjc = (float*)p;  p += BS * 4;
  float* refj = (float*)p; p += BS * 4;
  float* rden = (float*)p; p += BS * 4;

  f32tof16_k<<<12288, 256, 0, stream>>>(X0, X16, (int)BSD);
  f32tof16_k<<<1152, 256, 0, stream>>>(W, W16, 2 * DF * DF);
  pack_k<<<8192, 256, 0, stream>>>(mask, bmk);

  for (int l = 0; l < 2; ++l) {
    gemm1_k<<<dim3(128, 6), 256, 0, stream>>>(
        X16, W16 + (size_t)l * DF * DF, Wb + (size_t)l * DF,
        A + (size_t)l * 2 * DF, hT16, psi6, psj6);
    rowfin_k<<<16, 256, 0, stream>>>(psi6, psj6, Ab + l, si, sjc, refj);
    colsum_k<<<dim3(32, 16), 256, 0, stream>>>(bmk, si, sjc, refj, pden);
    colcomb_k<<<64, 256, 0, stream>>>(pden, rden);
    punorm2_k<<<dim3(32, 16), 256, 0, stream>>>(bmk, si, sjc, refj, rden, P16);
    gemm2_k<<<dim3(8, 6, 16), 256, 0, stream>>>(P16, hT16,
                                                out + (size_t)l * BSD, X16,
                                                (l == 0) ? 1 : 0);
  }
}

// Round 12
// 246.181 us; speedup vs baseline: 1.1236x; 1.1236x over previous
//
#include <hip/hip_runtime.h>
#include <cstddef>

#define SS 1024
#define DF 768
#define NBATCH 16
#define GAT_ALPHA 0.2f

typedef _Float16 f16x8 __attribute__((ext_vector_type(8)));
typedef _Float16 f16x4 __attribute__((ext_vector_type(4)));
typedef float f32x4 __attribute__((ext_vector_type(4)));

// async global->LDS, 16B per lane. LDS dest is wave-uniform base + lane*16.
__device__ __forceinline__ void gload16(const void* g, void* l) {
  __builtin_amdgcn_global_load_lds(
      (const __attribute__((address_space(1))) void*)g,
      (__attribute__((address_space(3))) void*)l, 16, 0, 0);
}

__device__ __forceinline__ float lrelu(float t) {
  return fmaxf(t, GAT_ALPHA * t);
}

// ---------------------------------------------------------------------------
// fp32 -> fp16 convert, 4 elems/thread
// ---------------------------------------------------------------------------
__global__ __launch_bounds__(256) void f32tof16_k(const float* __restrict__ in,
                                                  _Float16* __restrict__ out,
                                                  int n) {
  int idx = (blockIdx.x * 256 + threadIdx.x) * 4;
  if (idx + 3 < n) {
    float4 v = *(const float4*)&in[idx];
    f16x4 o;
    o[0] = (_Float16)v.x;
    o[1] = (_Float16)v.y;
    o[2] = (_Float16)v.z;
    o[3] = (_Float16)v.w;
    *(f16x4*)&out[idx] = o;
  }
}

// ---------------------------------------------------------------------------
// pack: int32 mask (64MB) -> bitmask (2MB). byte t holds j=8t..8t+7 (bit k).
// ---------------------------------------------------------------------------
__global__ __launch_bounds__(256) void pack_k(const int* __restrict__ mask,
                                              unsigned char* __restrict__ bm) {
  const size_t t = (size_t)blockIdx.x * 256 + threadIdx.x;  // byte idx, 2M
  const int* mp = mask + t * 8;
  const int4 a = *(const int4*)mp;
  const int4 c = *(const int4*)(mp + 4);
  unsigned v = (unsigned)(a.x > 0) | ((unsigned)(a.y > 0) << 1) |
               ((unsigned)(a.z > 0) << 2) | ((unsigned)(a.w > 0) << 3) |
               ((unsigned)(c.x > 0) << 4) | ((unsigned)(c.y > 0) << 5) |
               ((unsigned)(c.z > 0) << 6) | ((unsigned)(c.w > 0) << 7);
  bm[t] = (unsigned char)v;
}

// ===========================================================================
// GEMM1 (r9 proven): 8 waves, BM=128, BN=384, BK=32; 4-slot 128KB LDS ring;
// depth-2 prefetch; counted vmcnt(4); ONE barrier per K-tile.
// Epilogue: LDS transpose -> coalesced hT write + fused rowdots partials.
// ===========================================================================
__global__ __launch_bounds__(512, 2) void gemm1_k(
    const _Float16* __restrict__ X16, const _Float16* __restrict__ W16,
    const float* __restrict__ Wbl, const float* __restrict__ Al,
    _Float16* __restrict__ hT16, float* __restrict__ psi2,
    float* __restrict__ psj2) {
  __shared__ __align__(16) char smem[131072];  // 4 slots x 32KB
  const int flat = blockIdx.x;
  const int swz = (flat & 7) * 32 + (flat >> 3);  // XCD-chunked, 256%8==0
  const int m0 = (swz >> 1) * 128;
  const int n0 = (swz & 1) * 384;
  const int tid = threadIdx.x;
  const int w = tid >> 6, lane = tid & 63;

  const int srow = w * 16 + (lane >> 2);
  const int sk8 = ((lane & 3) ^ ((lane >> 3) & 3)) * 8;  // swizzled src chunk
  const int rby = ((lane >> 4) ^ ((lane >> 1) & 3)) * 16;  // swizzled read
  const int rrow = lane & 15;

  f32x4 acc[8][3];
#pragma unroll
  for (int mi = 0; mi < 8; ++mi)
#pragma unroll
    for (int ni = 0; ni < 3; ++ni) acc[mi][ni] = (f32x4)(0.f);

#define STGA1(s, kt)                                                       \
  gload16(&X16[(size_t)(m0 + srow) * DF + (kt) * 32 + sk8],                \
          smem + (s) * 32768 + w * 1024)
#define STGB1(s, kt, q)                                                    \
  gload16(&W16[(size_t)(n0 + (q) * 128 + srow) * DF + (kt) * 32 + sk8],    \
          smem + (s) * 32768 + 8192 + (q) * 8192 + w * 1024)

  const int NT = DF / 32;  // 24
  STGA1(0, 0); STGB1(0, 0, 0); STGB1(0, 0, 1); STGB1(0, 0, 2);
  STGA1(1, 1); STGB1(1, 1, 0); STGB1(1, 1, 1); STGB1(1, 1, 2);
  asm volatile("s_waitcnt vmcnt(4)" ::: "memory");
  asm volatile("s_barrier" ::: "memory");

  for (int t = 0; t < NT; ++t) {
    const int s = t & 3;
    const char* Ab = smem + s * 32768;
    const char* Bb = smem + s * 32768 + 8192;
    f16x8 bfr[3], afr[8];
#pragma unroll
    for (int ni = 0; ni < 3; ++ni)
      bfr[ni] = *(const f16x8*)(Bb + (w * 48 + ni * 16 + rrow) * 64 + rby);
#pragma unroll
    for (int mi = 0; mi < 8; ++mi)
      afr[mi] = *(const f16x8*)(Ab + (mi * 16 + rrow) * 64 + rby);
    if (t + 2 < NT) {
      const int s2 = (t + 2) & 3;
      STGA1(s2, t + 2);
      STGB1(s2, t + 2, 0);
      STGB1(s2, t + 2, 1);
      STGB1(s2, t + 2, 2);
    }
    if (t < NT - 2)
      asm volatile("s_waitcnt vmcnt(4)" ::: "memory");
    else
      asm volatile("s_waitcnt vmcnt(0)" ::: "memory");
    asm volatile("s_barrier" ::: "memory");
    __builtin_amdgcn_s_setprio(1);
#pragma unroll
    for (int mi = 0; mi < 8; ++mi)
#pragma unroll
      for (int ni = 0; ni < 3; ++ni)
        acc[mi][ni] = __builtin_amdgcn_mfma_f32_16x16x32_f16(
            afr[mi], bfr[ni], acc[mi][ni], 0, 0, 0);
    __builtin_amdgcn_s_setprio(0);
  }
#undef STGA1
#undef STGB1

  // ---- epilogue ----
  __syncthreads();
  _Float16* tb = (_Float16*)smem + (size_t)w * 6528;  // per-wave 48x136
  float* asrc = (float*)(smem + 104448);
  float* adst = asrc + 384;
  float* pwsi = adst + 384;
  float* pwsj = pwsi + 1024;

  for (int i = tid; i < 384; i += 512) {
    asrc[i] = Al[n0 + i];
    adst[i] = Al[DF + n0 + i];
  }
  const int cg = lane >> 4, cr = lane & 15;
  float bias[3];
#pragma unroll
  for (int ni = 0; ni < 3; ++ni) bias[ni] = Wbl[n0 + w * 48 + ni * 16 + cr];
#pragma unroll
  for (int mi = 0; mi < 8; ++mi) {
#pragma unroll
    for (int ni = 0; ni < 3; ++ni) {
      f16x4 tv;
#pragma unroll
      for (int r = 0; r < 4; ++r)
        tv[r] = (_Float16)(acc[mi][ni][r] + bias[ni]);
      *(f16x4*)&tb[(ni * 16 + cr) * 136 + mi * 16 + cg * 4] = tv;
    }
  }
  __syncthreads();

  const float* wa = asrc + w * 48;
  const float* wdp = adst + w * 48;
#pragma unroll
  for (int rr = 0; rr < 2; ++rr) {
    const int r = lane + rr * 64;
    float ps = 0.f, pd = 0.f;
#pragma unroll 8
    for (int c = 0; c < 48; ++c) {
      const float hv = (float)tb[c * 136 + r];
      ps = fmaf(hv, wa[c], ps);
      pd = fmaf(hv, wdp[c], pd);
    }
    pwsi[w * 128 + r] = ps;
    pwsj[w * 128 + r] = pd;
  }
  __syncthreads();
  if (tid < 128) {
    float s = 0.f, d2 = 0.f;
#pragma unroll
    for (int ww = 0; ww < 8; ++ww) {
      s += pwsi[ww * 128 + tid];
      d2 += pwsj[ww * 128 + tid];
    }
    const int nt = swz & 1;
    psi2[nt * 16384 + m0 + tid] = s;
    psj2[nt * 16384 + m0 + tid] = d2;
  }

  const int bb = m0 >> 10, s0 = m0 & 1023;
#pragma unroll
  for (int pass = 0; pass < 12; ++pass) {
    const int c = pass * 4 + (lane >> 4);
    f16x8 v = *(const f16x8*)&tb[c * 136 + (lane & 15) * 8];
    *(f16x8*)&hT16[((size_t)bb * DF + n0 + w * 48 + c) * SS + s0 +
                   (lane & 15) * 8] = v;
  }
}

// ===========================================================================
// GEMM2 flash: out[b,i,d] = sum_j P[i,j] * hT[d,j]; P computed IN-LOOP from
// bitmask + si + packed (sjc,q) f16x2 (q = exp(-refj)/den; q=-1/1024 encodes
// the all-masked uniform column). A-slot of the ring is ds_written (P tile
// t+1 during window t, swizzle-matched pos = c ^ ((r>>1)&3)); B staged via
// gload16 (3/window -> counted vmcnt(3)); lgkmcnt(0) before each barrier
// makes P-writes cross-wave visible. Slots: read t / write t+1 / laggard
// t-1 all distinct mod 4.
// ===========================================================================
__global__ __launch_bounds__(512, 2) void gemm2_k(
    const unsigned char* __restrict__ bmk, const float* __restrict__ si_g,
    const unsigned int* __restrict__ sq_g, const _Float16* __restrict__ hT16,
    float* __restrict__ outl, _Float16* __restrict__ X16n, int writeX) {
  // [0,131072) ring: slot s = A-P 8KB + B 24KB ; [131072,135168) sq ;
  // [135168,153600) mask 128 rows x 144B stride
  __shared__ __align__(16) char smem[153600];
  const int flat = blockIdx.x;
  const int swz = (flat & 7) * 32 + (flat >> 3);
  const int b = swz >> 4;
  const int i0 = ((swz >> 1) & 7) * 128;
  const int d0 = (swz & 1) * 384;
  const int tid = threadIdx.x;
  const int w = tid >> 6, lane = tid & 63;

  const int srow = w * 16 + (lane >> 2);
  const int sk8 = ((lane & 3) ^ ((lane >> 3) & 3)) * 8;
  const int rby = ((lane >> 4) ^ ((lane >> 1) & 3)) * 16;
  const int rrow = lane & 15;

  const int pr = tid >> 2, pc = tid & 3;  // P-compute: row, 8-j chunk
  const int ppos = pc ^ ((pr >> 1) & 3);  // swizzled write position

  const _Float16* hTb = hT16 + (size_t)b * DF * SS;

  f32x4 acc[8][3];
#pragma unroll
  for (int mi = 0; mi < 8; ++mi)
#pragma unroll
    for (int ni = 0; ni < 3; ++ni) acc[mi][ni] = (f32x4)(0.f);

#define STGB2(s, kt, q)                                                    \
  gload16(&hTb[((size_t)(d0 + (q) * 128 + srow)) * SS + (kt) * 32 + sk8],  \
          smem + (s) * 32768 + 8192 + (q) * 8192 + w * 1024)

#define COMPUTE_P(kt, slot)                                                  \
  {                                                                          \
    const unsigned mw =                                                      \
        *(const unsigned*)(smem + 135168 + pr * 144 + (kt) * 4);             \
    const unsigned mb = (mw >> (pc * 8)) & 0xffu;                            \
    const f16x8 sA_ =                                                        \
        *(const f16x8*)(smem + 131072 + (kt) * 128 + pc * 32);               \
    const f16x8 sB_ =                                                        \
        *(const f16x8*)(smem + 131072 + (kt) * 128 + pc * 32 + 16);          \
    f16x8 ph;                                                                \
    _Pragma("unroll") for (int jj = 0; jj < 4; ++jj) {                       \
      const float sjcv = (float)sA_[2 * jj];                                 \
      const float qv = (float)sA_[2 * jj + 1];                               \
      const float ttv = siv + sjcv;                                          \
      const float ev = __expf(fmaxf(ttv, 0.2f * ttv)) * qv;                  \
      ph[jj] = (_Float16)(qv < 0.f ? -qv : (((mb >> jj) & 1u) ? ev : 0.f));  \
    }                                                                        \
    _Pragma("unroll") for (int jj = 0; jj < 4; ++jj) {                       \
      const float sjcv = (float)sB_[2 * jj];                                 \
      const float qv = (float)sB_[2 * jj + 1];                               \
      const float ttv = siv + sjcv;                                          \
      const float ev = __expf(fmaxf(ttv, 0.2f * ttv)) * qv;                  \
      ph[4 + jj] = (_Float16)(qv < 0.f ? -qv                                 \
                                       : (((mb >> (4 + jj)) & 1u) ? ev       \
                                                                  : 0.f));   \
    }                                                                        \
    *(f16x8*)(smem + (slot) * 32768 + pr * 64 + ppos * 16) = ph;             \
  }

  // ---- prologue ----
  const unsigned char* bmb = bmk + ((size_t)b << 17) + ((size_t)i0 << 7);
  const uint4 mg0 = *(const uint4*)(bmb + tid * 32);
  const uint4 mg1 = *(const uint4*)(bmb + tid * 32 + 16);
  if (w < 4)
    gload16(&sq_g[(b << 10) + w * 256 + lane * 4], smem + 131072 + w * 1024);
  const float siv = si_g[(b << 10) + i0 + pr];
  const int NT = SS / 32;  // 32
  STGB2(0, 0, 0); STGB2(0, 0, 1); STGB2(0, 0, 2);
  STGB2(1, 1, 0); STGB2(1, 1, 1); STGB2(1, 1, 2);
  asm volatile("s_waitcnt vmcnt(0)" ::: "memory");
  *(uint4*)(smem + 135168 + pr * 144 + pc * 32) = mg0;
  *(uint4*)(smem + 135168 + pr * 144 + pc * 32 + 16) = mg1;
  asm volatile("s_waitcnt lgkmcnt(0)" ::: "memory");
  asm volatile("s_barrier" ::: "memory");
  COMPUTE_P(0, 0);
  asm volatile("s_waitcnt lgkmcnt(0)" ::: "memory");
  asm volatile("s_barrier" ::: "memory");

  for (int t = 0; t < NT; ++t) {
    const char* Ab = smem + (t & 3) * 32768;
    const char* Bb = Ab + 8192;
    f16x8 bfr[3], afr[8];
#pragma unroll
    for (int ni = 0; ni < 3; ++ni)
      bfr[ni] = *(const f16x8*)(Bb + (w * 48 + ni * 16 + rrow) * 64 + rby);
#pragma unroll
    for (int mi = 0; mi < 8; ++mi)
      afr[mi] = *(const f16x8*)(Ab + (mi * 16 + rrow) * 64 + rby);
    if (t + 1 < NT) COMPUTE_P(t + 1, (t + 1) & 3);
    if (t + 2 < NT) {
      const int s2 = (t + 2) & 3;
      STGB2(s2, t + 2, 0);
      STGB2(s2, t + 2, 1);
      STGB2(s2, t + 2, 2);
    }
    if (t < NT - 2)
      asm volatile("s_waitcnt vmcnt(3) lgkmcnt(0)" ::: "memory");
    else
      asm volatile("s_waitcnt vmcnt(0) lgkmcnt(0)" ::: "memory");
    asm volatile("s_barrier" ::: "memory");
    __builtin_amdgcn_s_setprio(1);
#pragma unroll
    for (int mi = 0; mi < 8; ++mi)
#pragma unroll
      for (int ni = 0; ni < 3; ++ni)
        acc[mi][ni] = __builtin_amdgcn_mfma_f32_16x16x32_f16(
            afr[mi], bfr[ni], acc[mi][ni], 0, 0, 0);
    __builtin_amdgcn_s_setprio(0);
  }
#undef STGB2
#undef COMPUTE_P

  const int cg = lane >> 4, cr = lane & 15;
#pragma unroll
  for (int mi = 0; mi < 8; ++mi) {
#pragma unroll
    for (int ni = 0; ni < 3; ++ni) {
      const int d = d0 + w * 48 + ni * 16 + cr;
      const int row0 = i0 + mi * 16 + cg * 4;
#pragma unroll
      for (int r = 0; r < 4; ++r) {
        float v = acc[mi][ni][r];
        size_t o = ((size_t)b * SS + row0 + r) * DF + d;
        outl[o] = v;
        if (writeX) X16n[o] = (_Float16)v;
      }
    }
  }
}

// ---------------------------------------------------------------------------
// rowfin: combine 2 n-tile partials -> si; per-batch max(si); sjc/refj.
// ---------------------------------------------------------------------------
__global__ __launch_bounds__(256) void rowfin_k(const float* __restrict__ psi2,
                                                const float* __restrict__ psj2,
                                                const float* __restrict__ Abp,
                                                float* __restrict__ si,
                                                float* __restrict__ sjc,
                                                float* __restrict__ refj) {
  const int b = blockIdx.x;
  const int t = threadIdx.x;
  __shared__ float red[256];
  float siv[4], sjv[4];
  float mloc = -1e30f;
#pragma unroll
  for (int q = 0; q < 4; ++q) {
    const int idx = (b << 10) + t + (q << 8);
    const float a = psi2[idx] + psi2[16384 + idx];
    const float d = psj2[idx] + psj2[16384 + idx];
    siv[q] = a;
    sjv[q] = d;
    si[idx] = a;
    mloc = fmaxf(mloc, a);
  }
  red[t] = mloc;
  __syncthreads();
  for (int off = 128; off > 0; off >>= 1) {
    if (t < off) red[t] = fmaxf(red[t], red[t + off]);
    __syncthreads();
  }
  const float maxsi = red[0];
  const float ab = Abp[0];
#pragma unroll
  for (int q = 0; q < 4; ++q) {
    const int idx = (b << 10) + t + (q << 8);
    const float c = sjv[q] + ab;
    sjc[idx] = c;
    refj[idx] = lrelu(maxsi + c);
  }
}

// ---------------------------------------------------------------------------
// colsum: column partial sums of exp(lrelu(si+sjc)-refj) over masked i.
// ---------------------------------------------------------------------------
__global__ __launch_bounds__(256) void colsum_k(
    const unsigned char* __restrict__ bm, const float* __restrict__ si,
    const float* __restrict__ sjc, const float* __restrict__ refj,
    float* __restrict__ pden) {
  const int g = blockIdx.x;  // 0..31
  const int b = blockIdx.y;  // 0..15
  const int t = threadIdx.x;
  const int jb = t & 127;
  const int half = t >> 7;
  const int row0 = (g << 5) + (half << 4);
  __shared__ float s_si[32];
  if (t < 32) s_si[t] = si[(b << 10) + (g << 5) + t];
  __syncthreads();
  float sc[8], rf[8];
  *(float4*)&sc[0] = *(const float4*)&sjc[(b << 10) + jb * 8];
  *(float4*)&sc[4] = *(const float4*)&sjc[(b << 10) + jb * 8 + 4];
  *(float4*)&rf[0] = *(const float4*)&refj[(b << 10) + jb * 8];
  *(float4*)&rf[4] = *(const float4*)&refj[(b << 10) + jb * 8 + 4];
  float den[8] = {0.f, 0.f, 0.f, 0.f, 0.f, 0.f, 0.f, 0.f};
  const unsigned char* bp = bm + ((size_t)b << 17) + ((size_t)row0 << 7) + jb;
#pragma unroll 4
  for (int r = 0; r < 16; ++r) {
    const unsigned m = bp[(size_t)r << 7];
    const float siv = s_si[(half << 4) + r];
#pragma unroll
    for (int k = 0; k < 8; ++k) {
      if ((m >> k) & 1) den[k] += __expf(lrelu(siv + sc[k]) - rf[k]);
    }
  }
  const size_t o = ((size_t)(g * 2 + half)) * 16384 + (b << 10) + jb * 8;
  *(float4*)&pden[o] = *(float4*)&den[0];
  *(float4*)&pden[o + 4] = *(float4*)&den[4];
}

// ---------------------------------------------------------------------------
// colfin: den = sum(pden); pack sq_g[b*1024+j] = f16x2(sjc, q) with
// q = exp(-refj)/den, or -1/1024 sentinel (all-masked -> uniform column).
// ---------------------------------------------------------------------------
__global__ __launch_bounds__(256) void colfin_k(const float* __restrict__ pden,
                                                const float* __restrict__ sjc,
                                                const float* __restrict__ refj,
                                                unsigned int* __restrict__ sq) {
  const int idx = blockIdx.x * 256 + threadIdx.x;  // b*1024 + j
  float s = 0.f;
#pragma unroll
  for (int c = 0; c < 64; ++c) s += pden[(size_t)c * 16384 + idx];
  const float q = (s > 0.f) ? __expf(-refj[idx]) / s : -0.0009765625f;
  const _Float16 h0 = (_Float16)sjc[idx];
  const _Float16 h1 = (_Float16)q;
  unsigned short u0, u1;
  __builtin_memcpy(&u0, &h0, 2);
  __builtin_memcpy(&u1, &h1, 2);
  sq[idx] = ((unsigned)u1 << 16) | (unsigned)u0;
}

// ---------------------------------------------------------------------------
extern "C" void kernel_launch(void* const* d_in, const int* in_sizes, int n_in,
                              void* d_out, int out_size, void* d_ws,
                              size_t ws_size, hipStream_t stream) {
  const float* X0 = (const float*)d_in[0];
  const int* mask = (const int*)d_in[1];
  const float* W = (const float*)d_in[2];
  const float* Wb = (const float*)d_in[3];
  const float* A = (const float*)d_in[4];
  const float* Ab = (const float*)d_in[5];
  float* out = (float*)d_out;

  const size_t BSD = (size_t)NBATCH * SS * DF;  // 12,582,912 elems
  const size_t BSS = (size_t)NBATCH * SS * SS;  // 16,777,216 elems
  const size_t BS = (size_t)NBATCH * SS;        // 16,384 elems

  char* p = (char*)d_ws;
  _Float16* X16 = (_Float16*)p;   p += BSD * 2;                   // 24 MB
  _Float16* hT16 = (_Float16*)p;  p += BSD * 2;                   // 24 MB
  _Float16* W16 = (_Float16*)p;   p += (size_t)2 * DF * DF * 2;   // 2.25 MB
  unsigned char* bmk = (unsigned char*)p; p += BSS / 8;           // 2 MB
  float* psi2 = (float*)p; p += 2 * BS * 4;   // 128 KB
  float* psj2 = (float*)p; p += 2 * BS * 4;   // 128 KB
  float* pden = (float*)p; p += 64 * BS * 4;  // 4 MB
  float* si = (float*)p;   p += BS * 4;
  float* sjc = (float*)p;  p += BS * 4;
  float* refj = (float*)p; p += BS * 4;
  unsigned int* sq_g = (unsigned int*)p; p += BS * 4;  // f16x2 packed

  f32tof16_k<<<12288, 256, 0, stream>>>(X0, X16, (int)BSD);
  f32tof16_k<<<1152, 256, 0, stream>>>(W, W16, 2 * DF * DF);
  pack_k<<<8192, 256, 0, stream>>>(mask, bmk);

  for (int l = 0; l < 2; ++l) {
    gemm1_k<<<256, 512, 0, stream>>>(X16, W16 + (size_t)l * DF * DF,
                                     Wb + (size_t)l * DF,
                                     A + (size_t)l * 2 * DF, hT16, psi2, psj2);
    rowfin_k<<<16, 256, 0, stream>>>(psi2, psj2, Ab + l, si, sjc, refj);
    colsum_k<<<dim3(32, 16), 256, 0, stream>>>(bmk, si, sjc, refj, pden);
    colfin_k<<<64, 256, 0, stream>>>(pden, sjc, refj, sq_g);
    gemm2_k<<<256, 512, 0, stream>>>(bmk, si, sq_g, hT16,
                                     out + (size_t)l * BSD, X16,
                                     (l == 0) ? 1 : 0);
  }
}

// Round 13
// 244.443 us; speedup vs baseline: 1.1315x; 1.0071x over previous
//
#include <hip/hip_runtime.h>
#include <cstddef>

#define SS 1024
#define DF 768
#define NBATCH 16
#define GAT_ALPHA 0.2f

typedef _Float16 f16x8 __attribute__((ext_vector_type(8)));
typedef _Float16 f16x4 __attribute__((ext_vector_type(4)));
typedef float f32x4 __attribute__((ext_vector_type(4)));

// async global->LDS, 16B per lane. LDS dest is wave-uniform base + lane*16.
__device__ __forceinline__ void gload16(const void* g, void* l) {
  __builtin_amdgcn_global_load_lds(
      (const __attribute__((address_space(1))) void*)g,
      (__attribute__((address_space(3))) void*)l, 16, 0, 0);
}

__device__ __forceinline__ float lrelu(float t) {
  return fmaxf(t, GAT_ALPHA * t);
}

// ---------------------------------------------------------------------------
// fp32 -> fp16 convert, 4 elems/thread
// ---------------------------------------------------------------------------
__global__ __launch_bounds__(256) void f32tof16_k(const float* __restrict__ in,
                                                  _Float16* __restrict__ out,
                                                  int n) {
  int idx = (blockIdx.x * 256 + threadIdx.x) * 4;
  if (idx + 3 < n) {
    float4 v = *(const float4*)&in[idx];
    f16x4 o;
    o[0] = (_Float16)v.x;
    o[1] = (_Float16)v.y;
    o[2] = (_Float16)v.z;
    o[3] = (_Float16)v.w;
    *(f16x4*)&out[idx] = o;
  }
}

// ---------------------------------------------------------------------------
// pack: int32 mask (64MB) -> bitmask (2MB). byte t holds j=8t..8t+7 (bit k).
// ---------------------------------------------------------------------------
__global__ __launch_bounds__(256) void pack_k(const int* __restrict__ mask,
                                              unsigned char* __restrict__ bm) {
  const size_t t = (size_t)blockIdx.x * 256 + threadIdx.x;  // byte idx, 2M
  const int* mp = mask + t * 8;
  const int4 a = *(const int4*)mp;
  const int4 c = *(const int4*)(mp + 4);
  unsigned v = (unsigned)(a.x > 0) | ((unsigned)(a.y > 0) << 1) |
               ((unsigned)(a.z > 0) << 2) | ((unsigned)(a.w > 0) << 3) |
               ((unsigned)(c.x > 0) << 4) | ((unsigned)(c.y > 0) << 5) |
               ((unsigned)(c.z > 0) << 6) | ((unsigned)(c.w > 0) << 7);
  bm[t] = (unsigned char)v;
}

// ===========================================================================
// GEMM1 (r9/r12 proven): 8 waves, BM=128, BN=384, BK=32; 4-slot LDS ring;
// depth-2 prefetch; counted vmcnt(4); ONE barrier per K-tile.
// Epilogue: LDS transpose -> coalesced hT write + fused rowdots partials.
// ===========================================================================
__global__ __launch_bounds__(512, 2) void gemm1_k(
    const _Float16* __restrict__ X16, const _Float16* __restrict__ W16,
    const float* __restrict__ Wbl, const float* __restrict__ Al,
    _Float16* __restrict__ hT16, float* __restrict__ psi2,
    float* __restrict__ psj2) {
  __shared__ __align__(16) char smem[131072];  // 4 slots x 32KB
  const int flat = blockIdx.x;
  const int swz = (flat & 7) * 32 + (flat >> 3);  // XCD-chunked, 256%8==0
  const int m0 = (swz >> 1) * 128;
  const int n0 = (swz & 1) * 384;
  const int tid = threadIdx.x;
  const int w = tid >> 6, lane = tid & 63;

  const int srow = w * 16 + (lane >> 2);
  const int sk8 = ((lane & 3) ^ ((lane >> 3) & 3)) * 8;  // swizzled src chunk
  const int rby = ((lane >> 4) ^ ((lane >> 1) & 3)) * 16;  // swizzled read
  const int rrow = lane & 15;

  f32x4 acc[8][3];
#pragma unroll
  for (int mi = 0; mi < 8; ++mi)
#pragma unroll
    for (int ni = 0; ni < 3; ++ni) acc[mi][ni] = (f32x4)(0.f);

#define STGA1(s, kt)                                                       \
  gload16(&X16[(size_t)(m0 + srow) * DF + (kt) * 32 + sk8],                \
          smem + (s) * 32768 + w * 1024)
#define STGB1(s, kt, q)                                                    \
  gload16(&W16[(size_t)(n0 + (q) * 128 + srow) * DF + (kt) * 32 + sk8],    \
          smem + (s) * 32768 + 8192 + (q) * 8192 + w * 1024)

  const int NT = DF / 32;  // 24
  STGA1(0, 0); STGB1(0, 0, 0); STGB1(0, 0, 1); STGB1(0, 0, 2);
  STGA1(1, 1); STGB1(1, 1, 0); STGB1(1, 1, 1); STGB1(1, 1, 2);
  asm volatile("s_waitcnt vmcnt(4)" ::: "memory");
  asm volatile("s_barrier" ::: "memory");

  for (int t = 0; t < NT; ++t) {
    const int s = t & 3;
    const char* Ab = smem + s * 32768;
    const char* Bb = smem + s * 32768 + 8192;
    f16x8 bfr[3], afr[8];
#pragma unroll
    for (int ni = 0; ni < 3; ++ni)
      bfr[ni] = *(const f16x8*)(Bb + (w * 48 + ni * 16 + rrow) * 64 + rby);
#pragma unroll
    for (int mi = 0; mi < 8; ++mi)
      afr[mi] = *(const f16x8*)(Ab + (mi * 16 + rrow) * 64 + rby);
    if (t + 2 < NT) {
      const int s2 = (t + 2) & 3;
      STGA1(s2, t + 2);
      STGB1(s2, t + 2, 0);
      STGB1(s2, t + 2, 1);
      STGB1(s2, t + 2, 2);
    }
    if (t < NT - 2)
      asm volatile("s_waitcnt vmcnt(4)" ::: "memory");
    else
      asm volatile("s_waitcnt vmcnt(0)" ::: "memory");
    asm volatile("s_barrier" ::: "memory");
    __builtin_amdgcn_s_setprio(1);
#pragma unroll
    for (int mi = 0; mi < 8; ++mi)
#pragma unroll
      for (int ni = 0; ni < 3; ++ni)
        acc[mi][ni] = __builtin_amdgcn_mfma_f32_16x16x32_f16(
            afr[mi], bfr[ni], acc[mi][ni], 0, 0, 0);
    __builtin_amdgcn_s_setprio(0);
  }
#undef STGA1
#undef STGB1

  // ---- epilogue ----
  __syncthreads();
  _Float16* tb = (_Float16*)smem + (size_t)w * 6528;  // per-wave 48x136
  float* asrc = (float*)(smem + 104448);
  float* adst = asrc + 384;
  float* pwsi = adst + 384;
  float* pwsj = pwsi + 1024;

  for (int i = tid; i < 384; i += 512) {
    asrc[i] = Al[n0 + i];
    adst[i] = Al[DF + n0 + i];
  }
  const int cg = lane >> 4, cr = lane & 15;
  float bias[3];
#pragma unroll
  for (int ni = 0; ni < 3; ++ni) bias[ni] = Wbl[n0 + w * 48 + ni * 16 + cr];
#pragma unroll
  for (int mi = 0; mi < 8; ++mi) {
#pragma unroll
    for (int ni = 0; ni < 3; ++ni) {
      f16x4 tv;
#pragma unroll
      for (int r = 0; r < 4; ++r)
        tv[r] = (_Float16)(acc[mi][ni][r] + bias[ni]);
      *(f16x4*)&tb[(ni * 16 + cr) * 136 + mi * 16 + cg * 4] = tv;
    }
  }
  __syncthreads();

  const float* wa = asrc + w * 48;
  const float* wdp = adst + w * 48;
#pragma unroll
  for (int rr = 0; rr < 2; ++rr) {
    const int r = lane + rr * 64;
    float ps = 0.f, pd = 0.f;
#pragma unroll 8
    for (int c = 0; c < 48; ++c) {
      const float hv = (float)tb[c * 136 + r];
      ps = fmaf(hv, wa[c], ps);
      pd = fmaf(hv, wdp[c], pd);
    }
    pwsi[w * 128 + r] = ps;
    pwsj[w * 128 + r] = pd;
  }
  __syncthreads();
  if (tid < 128) {
    float s = 0.f, d2 = 0.f;
#pragma unroll
    for (int ww = 0; ww < 8; ++ww) {
      s += pwsi[ww * 128 + tid];
      d2 += pwsj[ww * 128 + tid];
    }
    const int nt = swz & 1;
    psi2[nt * 16384 + m0 + tid] = s;
    psj2[nt * 16384 + m0 + tid] = d2;
  }

  const int bb = m0 >> 10, s0 = m0 & 1023;
#pragma unroll
  for (int pass = 0; pass < 12; ++pass) {
    const int c = pass * 4 + (lane >> 4);
    f16x8 v = *(const f16x8*)&tb[c * 136 + (lane & 15) * 8];
    *(f16x8*)&hT16[((size_t)bb * DF + n0 + w * 48 + c) * SS + s0 +
                   (lane & 15) * 8] = v;
  }
}

// ===========================================================================
// GEMM2 flash v2: P computed IN-LOOP, factorized (NO exp in K-loop):
//   P = mask ? (si+sjc>=0 ? e^si*c1[j] : e^{0.2si}*c2[j]) : 0
//   c1 = e^{sjc-refj}/den, c2 = e^{0.2sjc-refj}/den (f16, packed 8B/j);
//   c2<0 sentinel = all-masked uniform column (P = 1/1024, mask ignored).
// Continuity of exp(lrelu) at t=0 makes the f16 sign test exact-safe.
// Ring/barrier/vmcnt schedule identical to r12 (proven).
// ===========================================================================
__global__ __launch_bounds__(512, 2) void gemm2_k(
    const unsigned char* __restrict__ bmk, const float* __restrict__ si_g,
    const uint2* __restrict__ sq_g, const _Float16* __restrict__ hT16,
    float* __restrict__ outl, _Float16* __restrict__ X16n, int writeX) {
  // [0,131072) ring: slot = A-P 8KB + B 24KB ; [131072,139264) sq (8B/j);
  // [139264,157696) mask 128 rows x 144B
  __shared__ __align__(16) char smem[157696];
  const int flat = blockIdx.x;
  const int swz = (flat & 7) * 32 + (flat >> 3);
  const int b = swz >> 4;
  const int i0 = ((swz >> 1) & 7) * 128;
  const int d0 = (swz & 1) * 384;
  const int tid = threadIdx.x;
  const int w = tid >> 6, lane = tid & 63;

  const int srow = w * 16 + (lane >> 2);
  const int sk8 = ((lane & 3) ^ ((lane >> 3) & 3)) * 8;
  const int rby = ((lane >> 4) ^ ((lane >> 1) & 3)) * 16;
  const int rrow = lane & 15;

  const int pr = tid >> 2, pc = tid & 3;  // P-compute: row, 8-j chunk
  const int ppos = pc ^ ((pr >> 1) & 3);  // swizzled write position

  const _Float16* hTb = hT16 + (size_t)b * DF * SS;

  f32x4 acc[8][3];
#pragma unroll
  for (int mi = 0; mi < 8; ++mi)
#pragma unroll
    for (int ni = 0; ni < 3; ++ni) acc[mi][ni] = (f32x4)(0.f);

#define STGB2(s, kt, q)                                                    \
  gload16(&hTb[((size_t)(d0 + (q) * 128 + srow)) * SS + (kt) * 32 + sk8],  \
          smem + (s) * 32768 + 8192 + (q) * 8192 + w * 1024)

  // PCALC: factorized P, all-f16, no transcendental
#define PCALC(sjch, c1h, c2h, mbit)                                        \
  ((c2h) < (_Float16)0.f                                                   \
       ? (_Float16)0.0009765625f                                           \
       : (!(mbit) ? (_Float16)0.f                                          \
                  : ((_Float16)(sih + (sjch)) >= (_Float16)0.f             \
                         ? (_Float16)(e1h * (c1h))                         \
                         : (_Float16)(e2h * (c2h)))))

#define COMPUTE_P(kt, slot)                                                  \
  {                                                                          \
    const unsigned mw =                                                      \
        *(const unsigned*)(smem + 139264 + pr * 144 + (kt) * 4);             \
    const unsigned mb = (mw >> (pc * 8)) & 0xffu;                            \
    const char* sqb = smem + 131072 + (kt) * 256 + pc * 64;                  \
    const f16x8 q0 = *(const f16x8*)(sqb);                                   \
    const f16x8 q1 = *(const f16x8*)(sqb + 16);                              \
    const f16x8 q2 = *(const f16x8*)(sqb + 32);                              \
    const f16x8 q3 = *(const f16x8*)(sqb + 48);                              \
    f16x8 ph;                                                                \
    ph[0] = PCALC(q0[0], q0[1], q0[2], (mb & 1u));                           \
    ph[1] = PCALC(q0[4], q0[5], q0[6], ((mb >> 1) & 1u));                    \
    ph[2] = PCALC(q1[0], q1[1], q1[2], ((mb >> 2) & 1u));                    \
    ph[3] = PCALC(q1[4], q1[5], q1[6], ((mb >> 3) & 1u));                    \
    ph[4] = PCALC(q2[0], q2[1], q2[2], ((mb >> 4) & 1u));                    \
    ph[5] = PCALC(q2[4], q2[5], q2[6], ((mb >> 5) & 1u));                    \
    ph[6] = PCALC(q3[0], q3[1], q3[2], ((mb >> 6) & 1u));                    \
    ph[7] = PCALC(q3[4], q3[5], q3[6], ((mb >> 7) & 1u));                    \
    *(f16x8*)(smem + (slot) * 32768 + pr * 64 + ppos * 16) = ph;             \
  }

  // ---- prologue ----
  const unsigned char* bmb = bmk + ((size_t)b << 17) + ((size_t)i0 << 7);
  const uint4 mg0 = *(const uint4*)(bmb + tid * 32);
  const uint4 mg1 = *(const uint4*)(bmb + tid * 32 + 16);
  // sq: 1024 j x 8B = 8KB; all 512 threads load 16B each
  gload16((const char*)(sq_g + ((size_t)b << 10)) + tid * 16,
          smem + 131072 + w * 1024);
  const float siv = si_g[(b << 10) + i0 + pr];
  const _Float16 sih = (_Float16)siv;
  const _Float16 e1h = (_Float16)__expf(siv);
  const _Float16 e2h = (_Float16)__expf(0.2f * siv);
  const int NT = SS / 32;  // 32
  STGB2(0, 0, 0); STGB2(0, 0, 1); STGB2(0, 0, 2);
  STGB2(1, 1, 0); STGB2(1, 1, 1); STGB2(1, 1, 2);
  asm volatile("s_waitcnt vmcnt(0)" ::: "memory");
  *(uint4*)(smem + 139264 + pr * 144 + pc * 32) = mg0;
  *(uint4*)(smem + 139264 + pr * 144 + pc * 32 + 16) = mg1;
  asm volatile("s_waitcnt lgkmcnt(0)" ::: "memory");
  asm volatile("s_barrier" ::: "memory");
  COMPUTE_P(0, 0);
  asm volatile("s_waitcnt lgkmcnt(0)" ::: "memory");
  asm volatile("s_barrier" ::: "memory");

  for (int t = 0; t < NT; ++t) {
    const char* Ab = smem + (t & 3) * 32768;
    const char* Bb = Ab + 8192;
    f16x8 bfr[3], afr[8];
#pragma unroll
    for (int ni = 0; ni < 3; ++ni)
      bfr[ni] = *(const f16x8*)(Bb + (w * 48 + ni * 16 + rrow) * 64 + rby);
#pragma unroll
    for (int mi = 0; mi < 8; ++mi)
      afr[mi] = *(const f16x8*)(Ab + (mi * 16 + rrow) * 64 + rby);
    if (t + 1 < NT) COMPUTE_P(t + 1, (t + 1) & 3);
    if (t + 2 < NT) {
      const int s2 = (t + 2) & 3;
      STGB2(s2, t + 2, 0);
      STGB2(s2, t + 2, 1);
      STGB2(s2, t + 2, 2);
    }
    if (t < NT - 2)
      asm volatile("s_waitcnt vmcnt(3) lgkmcnt(0)" ::: "memory");
    else
      asm volatile("s_waitcnt vmcnt(0) lgkmcnt(0)" ::: "memory");
    asm volatile("s_barrier" ::: "memory");
    __builtin_amdgcn_s_setprio(1);
#pragma unroll
    for (int mi = 0; mi < 8; ++mi)
#pragma unroll
      for (int ni = 0; ni < 3; ++ni)
        acc[mi][ni] = __builtin_amdgcn_mfma_f32_16x16x32_f16(
            afr[mi], bfr[ni], acc[mi][ni], 0, 0, 0);
    __builtin_amdgcn_s_setprio(0);
  }
#undef STGB2
#undef COMPUTE_P
#undef PCALC

  const int cg = lane >> 4, cr = lane & 15;
#pragma unroll
  for (int mi = 0; mi < 8; ++mi) {
#pragma unroll
    for (int ni = 0; ni < 3; ++ni) {
      const int d = d0 + w * 48 + ni * 16 + cr;
      const int row0 = i0 + mi * 16 + cg * 4;
#pragma unroll
      for (int r = 0; r < 4; ++r) {
        float v = acc[mi][ni][r];
        size_t o = ((size_t)b * SS + row0 + r) * DF + d;
        outl[o] = v;
        if (writeX) X16n[o] = (_Float16)v;
      }
    }
  }
}

// ---------------------------------------------------------------------------
// rowfin: combine 2 n-tile partials -> si; per-batch max(si); sjc/refj.
// ---------------------------------------------------------------------------
__global__ __launch_bounds__(256) void rowfin_k(const float* __restrict__ psi2,
                                                const float* __restrict__ psj2,
                                                const float* __restrict__ Abp,
                                                float* __restrict__ si,
                                                float* __restrict__ sjc,
                                                float* __restrict__ refj) {
  const int b = blockIdx.x;
  const int t = threadIdx.x;
  __shared__ float red[256];
  float siv[4], sjv[4];
  float mloc = -1e30f;
#pragma unroll
  for (int q = 0; q < 4; ++q) {
    const int idx = (b << 10) + t + (q << 8);
    const float a = psi2[idx] + psi2[16384 + idx];
    const float d = psj2[idx] + psj2[16384 + idx];
    siv[q] = a;
    sjv[q] = d;
    si[idx] = a;
    mloc = fmaxf(mloc, a);
  }
  red[t] = mloc;
  __syncthreads();
  for (int off = 128; off > 0; off >>= 1) {
    if (t < off) red[t] = fmaxf(red[t], red[t + off]);
    __syncthreads();
  }
  const float maxsi = red[0];
  const float ab = Abp[0];
#pragma unroll
  for (int q = 0; q < 4; ++q) {
    const int idx = (b << 10) + t + (q << 8);
    const float c = sjv[q] + ab;
    sjc[idx] = c;
    refj[idx] = lrelu(maxsi + c);
  }
}

// ---------------------------------------------------------------------------
// colsum v2 (factorized, no exp): per column j accumulate
//   S1 = sum_{masked i, si+sjc>=0} e^{si},  S2 = sum_{masked i, si+sjc<0} e^{0.2 si}
// ---------------------------------------------------------------------------
__global__ __launch_bounds__(256) void colsum_k(
    const unsigned char* __restrict__ bm, const float* __restrict__ si,
    const float* __restrict__ sjc, float* __restrict__ pden1,
    float* __restrict__ pden2) {
  const int g = blockIdx.x;  // 0..31
  const int b = blockIdx.y;  // 0..15
  const int t = threadIdx.x;
  const int jb = t & 127;
  const int half = t >> 7;
  const int row0 = (g << 5) + (half << 4);
  __shared__ float s_si[32], s_e1[32], s_e2[32];
  if (t < 32) {
    const float v = si[(b << 10) + (g << 5) + t];
    s_si[t] = v;
    s_e1[t] = __expf(v);
    s_e2[t] = __expf(0.2f * v);
  }
  __syncthreads();
  float sc[8];
  *(float4*)&sc[0] = *(const float4*)&sjc[(b << 10) + jb * 8];
  *(float4*)&sc[4] = *(const float4*)&sjc[(b << 10) + jb * 8 + 4];
  float d1[8] = {0.f, 0.f, 0.f, 0.f, 0.f, 0.f, 0.f, 0.f};
  float d2[8] = {0.f, 0.f, 0.f, 0.f, 0.f, 0.f, 0.f, 0.f};
  const unsigned char* bp = bm + ((size_t)b << 17) + ((size_t)row0 << 7) + jb;
#pragma unroll 4
  for (int r = 0; r < 16; ++r) {
    const unsigned m = bp[(size_t)r << 7];
    const int ri = (half << 4) + r;
    const float siv = s_si[ri], e1v = s_e1[ri], e2v = s_e2[ri];
#pragma unroll
    for (int k = 0; k < 8; ++k) {
      if ((m >> k) & 1) {
        if (siv + sc[k] >= 0.f)
          d1[k] += e1v;
        else
          d2[k] += e2v;
      }
    }
  }
  const size_t o = ((size_t)(g * 2 + half)) * 16384 + (b << 10) + jb * 8;
  *(float4*)&pden1[o] = *(float4*)&d1[0];
  *(float4*)&pden1[o + 4] = *(float4*)&d1[4];
  *(float4*)&pden2[o] = *(float4*)&d2[0];
  *(float4*)&pden2[o + 4] = *(float4*)&d2[4];
}

// ---------------------------------------------------------------------------
// colfin v2: den = e^{sjc-refj}*S1 + e^{0.2sjc-refj}*S2; pack per j (8B):
//   halves [sjc, c1, c2, 0] with c1=e^{sjc-refj}/den, c2=e^{0.2sjc-refj}/den;
//   all-masked column -> c2 = -1/1024 sentinel.
// ---------------------------------------------------------------------------
__global__ __launch_bounds__(256) void colfin_k(
    const float* __restrict__ pden1, const float* __restrict__ pden2,
    const float* __restrict__ sjc, const float* __restrict__ refj,
    uint2* __restrict__ sq) {
  const int idx = blockIdx.x * 256 + threadIdx.x;  // b*1024 + j
  float S1 = 0.f, S2 = 0.f;
#pragma unroll
  for (int c = 0; c < 64; ++c) {
    S1 += pden1[(size_t)c * 16384 + idx];
    S2 += pden2[(size_t)c * 16384 + idx];
  }
  const float sj = sjc[idx], rf = refj[idx];
  const float A1 = __expf(sj - rf);
  const float A2 = __expf(0.2f * sj - rf);
  const float den = A1 * S1 + A2 * S2;
  _Float16 sjh = (_Float16)sj;
  _Float16 c1h, c2h;
  if (den > 0.f) {
    c1h = (_Float16)(A1 / den);
    c2h = (_Float16)(A2 / den);
  } else {
    c1h = (_Float16)0.f;
    c2h = (_Float16)(-0.0009765625f);
  }
  unsigned short u0, u1, u2;
  __builtin_memcpy(&u0, &sjh, 2);
  __builtin_memcpy(&u1, &c1h, 2);
  __builtin_memcpy(&u2, &c2h, 2);
  uint2 outw;
  outw.x = (unsigned)u0 | ((unsigned)u1 << 16);
  outw.y = (unsigned)u2;
  sq[idx] = outw;
}

// ---------------------------------------------------------------------------
extern "C" void kernel_launch(void* const* d_in, const int* in_sizes, int n_in,
                              void* d_out, int out_size, void* d_ws,
                              size_t ws_size, hipStream_t stream) {
  const float* X0 = (const float*)d_in[0];
  const int* mask = (const int*)d_in[1];
  const float* W = (const float*)d_in[2];
  const float* Wb = (const float*)d_in[3];
  const float* A = (const float*)d_in[4];
  const float* Ab = (const float*)d_in[5];
  float* out = (float*)d_out;

  const size_t BSD = (size_t)NBATCH * SS * DF;  // 12,582,912 elems
  const size_t BSS = (size_t)NBATCH * SS * SS;  // 16,777,216 elems
  const size_t BS = (size_t)NBATCH * SS;        // 16,384 elems

  char* p = (char*)d_ws;
  _Float16* X16 = (_Float16*)p;   p += BSD * 2;                   // 24 MB
  _Float16* hT16 = (_Float16*)p;  p += BSD * 2;                   // 24 MB
  _Float16* W16 = (_Float16*)p;   p += (size_t)2 * DF * DF * 2;   // 2.25 MB
  unsigned char* bmk = (unsigned char*)p; p += BSS / 8;           // 2 MB
  float* psi2 = (float*)p;  p += 2 * BS * 4;   // 128 KB
  float* psj2 = (float*)p;  p += 2 * BS * 4;   // 128 KB
  float* pden1 = (float*)p; p += 64 * BS * 4;  // 4 MB
  float* pden2 = (float*)p; p += 64 * BS * 4;  // 4 MB
  float* si = (float*)p;   p += BS * 4;
  float* sjc = (float*)p;  p += BS * 4;
  float* refj = (float*)p; p += BS * 4;
  uint2* sq_g = (uint2*)p; p += BS * 8;  // 8B/j packed (sjc,c1,c2)

  f32tof16_k<<<12288, 256, 0, stream>>>(X0, X16, (int)BSD);
  f32tof16_k<<<1152, 256, 0, stream>>>(W, W16, 2 * DF * DF);
  pack_k<<<8192, 256, 0, stream>>>(mask, bmk);

  for (int l = 0; l < 2; ++l) {
    gemm1_k<<<256, 512, 0, stream>>>(X16, W16 + (size_t)l * DF * DF,
                                     Wb + (size_t)l * DF,
                                     A + (size_t)l * 2 * DF, hT16, psi2, psj2);
    rowfin_k<<<16, 256, 0, stream>>>(psi2, psj2, Ab + l, si, sjc, refj);
    colsum_k<<<dim3(32, 16), 256, 0, stream>>>(bmk, si, sjc, pden1, pden2);
    colfin_k<<<64, 256, 0, stream>>>(pden1, pden2, sjc, refj, sq_g);
    gemm2_k<<<256, 512, 0, stream>>>(bmk, si, sq_g, hT16,
                                     out + (size_t)l * BSD, X16,
                                     (l == 0) ? 1 : 0);
  }
}

// Round 14
// 236.508 us; speedup vs baseline: 1.1695x; 1.0335x over previous
//
#include <hip/hip_runtime.h>
#include <cstddef>

#define SS 1024
#define DF 768
#define NBATCH 16
#define GAT_ALPHA 0.2f

typedef _Float16 f16x8 __attribute__((ext_vector_type(8)));
typedef _Float16 f16x4 __attribute__((ext_vector_type(4)));
typedef float f32x4 __attribute__((ext_vector_type(4)));

// async global->LDS, 16B per lane. LDS dest is wave-uniform base + lane*16.
__device__ __forceinline__ void gload16(const void* g, void* l) {
  __builtin_amdgcn_global_load_lds(
      (const __attribute__((address_space(1))) void*)g,
      (__attribute__((address_space(3))) void*)l, 16, 0, 0);
}

__device__ __forceinline__ float lrelu(float t) {
  return fmaxf(t, GAT_ALPHA * t);
}

// ---------------------------------------------------------------------------
// pre: fused prologue. blocks [0,12288): X f32->f16; [12288,13440): W f32->f16;
// [13440,21632): mask int32 -> bitmask.
// ---------------------------------------------------------------------------
__global__ __launch_bounds__(256) void pre_k(const float* __restrict__ X0,
                                             _Float16* __restrict__ X16,
                                             const float* __restrict__ W,
                                             _Float16* __restrict__ W16,
                                             const int* __restrict__ mask,
                                             unsigned char* __restrict__ bm) {
  const int bid = blockIdx.x;
  if (bid < 13440) {
    const float* in = (bid < 12288) ? X0 : W;
    _Float16* out = (bid < 12288) ? X16 : W16;
    const int base = (bid < 12288) ? bid : (bid - 12288);
    const int idx = (base * 256 + (int)threadIdx.x) * 4;
    float4 v = *(const float4*)&in[idx];
    f16x4 o;
    o[0] = (_Float16)v.x;
    o[1] = (_Float16)v.y;
    o[2] = (_Float16)v.z;
    o[3] = (_Float16)v.w;
    *(f16x4*)&out[idx] = o;
  } else {
    const size_t t = (size_t)(bid - 13440) * 256 + threadIdx.x;  // byte idx
    const int* mp = mask + t * 8;
    const int4 a = *(const int4*)mp;
    const int4 c = *(const int4*)(mp + 4);
    unsigned v = (unsigned)(a.x > 0) | ((unsigned)(a.y > 0) << 1) |
                 ((unsigned)(a.z > 0) << 2) | ((unsigned)(a.w > 0) << 3) |
                 ((unsigned)(c.x > 0) << 4) | ((unsigned)(c.y > 0) << 5) |
                 ((unsigned)(c.z > 0) << 6) | ((unsigned)(c.w > 0) << 7);
    bm[t] = (unsigned char)v;
  }
}

// ===========================================================================
// GEMM1 (r9/r12 proven): 8 waves, BM=128, BN=384, BK=32; 4-slot LDS ring;
// depth-2 prefetch; counted vmcnt(4); ONE barrier per K-tile.
// Epilogue: LDS transpose -> coalesced hT write + fused rowdots partials.
// ===========================================================================
__global__ __launch_bounds__(512, 2) void gemm1_k(
    const _Float16* __restrict__ X16, const _Float16* __restrict__ W16,
    const float* __restrict__ Wbl, const float* __restrict__ Al,
    _Float16* __restrict__ hT16, float* __restrict__ psi2,
    float* __restrict__ psj2) {
  __shared__ __align__(16) char smem[131072];  // 4 slots x 32KB
  const int flat = blockIdx.x;
  const int swz = (flat & 7) * 32 + (flat >> 3);  // XCD-chunked, 256%8==0
  const int m0 = (swz >> 1) * 128;
  const int n0 = (swz & 1) * 384;
  const int tid = threadIdx.x;
  const int w = tid >> 6, lane = tid & 63;

  const int srow = w * 16 + (lane >> 2);
  const int sk8 = ((lane & 3) ^ ((lane >> 3) & 3)) * 8;  // swizzled src chunk
  const int rby = ((lane >> 4) ^ ((lane >> 1) & 3)) * 16;  // swizzled read
  const int rrow = lane & 15;

  f32x4 acc[8][3];
#pragma unroll
  for (int mi = 0; mi < 8; ++mi)
#pragma unroll
    for (int ni = 0; ni < 3; ++ni) acc[mi][ni] = (f32x4)(0.f);

#define STGA1(s, kt)                                                       \
  gload16(&X16[(size_t)(m0 + srow) * DF + (kt) * 32 + sk8],                \
          smem + (s) * 32768 + w * 1024)
#define STGB1(s, kt, q)                                                    \
  gload16(&W16[(size_t)(n0 + (q) * 128 + srow) * DF + (kt) * 32 + sk8],    \
          smem + (s) * 32768 + 8192 + (q) * 8192 + w * 1024)

  const int NT = DF / 32;  // 24
  STGA1(0, 0); STGB1(0, 0, 0); STGB1(0, 0, 1); STGB1(0, 0, 2);
  STGA1(1, 1); STGB1(1, 1, 0); STGB1(1, 1, 1); STGB1(1, 1, 2);
  asm volatile("s_waitcnt vmcnt(4)" ::: "memory");
  asm volatile("s_barrier" ::: "memory");

  for (int t = 0; t < NT; ++t) {
    const int s = t & 3;
    const char* Ab = smem + s * 32768;
    const char* Bb = smem + s * 32768 + 8192;
    f16x8 bfr[3], afr[8];
#pragma unroll
    for (int ni = 0; ni < 3; ++ni)
      bfr[ni] = *(const f16x8*)(Bb + (w * 48 + ni * 16 + rrow) * 64 + rby);
#pragma unroll
    for (int mi = 0; mi < 8; ++mi)
      afr[mi] = *(const f16x8*)(Ab + (mi * 16 + rrow) * 64 + rby);
    if (t + 2 < NT) {
      const int s2 = (t + 2) & 3;
      STGA1(s2, t + 2);
      STGB1(s2, t + 2, 0);
      STGB1(s2, t + 2, 1);
      STGB1(s2, t + 2, 2);
    }
    if (t < NT - 2)
      asm volatile("s_waitcnt vmcnt(4)" ::: "memory");
    else
      asm volatile("s_waitcnt vmcnt(0)" ::: "memory");
    asm volatile("s_barrier" ::: "memory");
    __builtin_amdgcn_s_setprio(1);
#pragma unroll
    for (int mi = 0; mi < 8; ++mi)
#pragma unroll
      for (int ni = 0; ni < 3; ++ni)
        acc[mi][ni] = __builtin_amdgcn_mfma_f32_16x16x32_f16(
            afr[mi], bfr[ni], acc[mi][ni], 0, 0, 0);
    __builtin_amdgcn_s_setprio(0);
  }
#undef STGA1
#undef STGB1

  // ---- epilogue ----
  __syncthreads();
  _Float16* tb = (_Float16*)smem + (size_t)w * 6528;  // per-wave 48x136
  float* asrc = (float*)(smem + 104448);
  float* adst = asrc + 384;
  float* pwsi = adst + 384;
  float* pwsj = pwsi + 1024;

  for (int i = tid; i < 384; i += 512) {
    asrc[i] = Al[n0 + i];
    adst[i] = Al[DF + n0 + i];
  }
  const int cg = lane >> 4, cr = lane & 15;
  float bias[3];
#pragma unroll
  for (int ni = 0; ni < 3; ++ni) bias[ni] = Wbl[n0 + w * 48 + ni * 16 + cr];
#pragma unroll
  for (int mi = 0; mi < 8; ++mi) {
#pragma unroll
    for (int ni = 0; ni < 3; ++ni) {
      f16x4 tv;
#pragma unroll
      for (int r = 0; r < 4; ++r)
        tv[r] = (_Float16)(acc[mi][ni][r] + bias[ni]);
      *(f16x4*)&tb[(ni * 16 + cr) * 136 + mi * 16 + cg * 4] = tv;
    }
  }
  __syncthreads();

  const float* wa = asrc + w * 48;
  const float* wdp = adst + w * 48;
#pragma unroll
  for (int rr = 0; rr < 2; ++rr) {
    const int r = lane + rr * 64;
    float ps = 0.f, pd = 0.f;
#pragma unroll 8
    for (int c = 0; c < 48; ++c) {
      const float hv = (float)tb[c * 136 + r];
      ps = fmaf(hv, wa[c], ps);
      pd = fmaf(hv, wdp[c], pd);
    }
    pwsi[w * 128 + r] = ps;
    pwsj[w * 128 + r] = pd;
  }
  __syncthreads();
  if (tid < 128) {
    float s = 0.f, d2 = 0.f;
#pragma unroll
    for (int ww = 0; ww < 8; ++ww) {
      s += pwsi[ww * 128 + tid];
      d2 += pwsj[ww * 128 + tid];
    }
    const int nt = swz & 1;
    psi2[nt * 16384 + m0 + tid] = s;
    psj2[nt * 16384 + m0 + tid] = d2;
  }

  const int bb = m0 >> 10, s0 = m0 & 1023;
#pragma unroll
  for (int pass = 0; pass < 12; ++pass) {
    const int c = pass * 4 + (lane >> 4);
    f16x8 v = *(const f16x8*)&tb[c * 136 + (lane & 15) * 8];
    *(f16x8*)&hT16[((size_t)bb * DF + n0 + w * 48 + c) * SS + s0 +
                   (lane & 15) * 8] = v;
  }
}

// ===========================================================================
// GEMM2 flash (r12/r13 proven schedule): P computed IN-LOOP, factorized:
//   P = mask ? (si+sjc>=0 ? e^si*c1[j] : e^{0.2si}*c2[j]) : 0
//   c2<0 sentinel = all-masked uniform column (P = 1/1024, mask ignored).
// si read directly from psi2 partial pair (rowfin deleted).
// ===========================================================================
__global__ __launch_bounds__(512, 2) void gemm2_k(
    const unsigned char* __restrict__ bmk, const float* __restrict__ psi2,
    const uint2* __restrict__ sq_g, const _Float16* __restrict__ hT16,
    float* __restrict__ outl, _Float16* __restrict__ X16n, int writeX) {
  // [0,131072) ring: slot = A-P 8KB + B 24KB ; [131072,139264) sq (8B/j);
  // [139264,157696) mask 128 rows x 144B
  __shared__ __align__(16) char smem[157696];
  const int flat = blockIdx.x;
  const int swz = (flat & 7) * 32 + (flat >> 3);
  const int b = swz >> 4;
  const int i0 = ((swz >> 1) & 7) * 128;
  const int d0 = (swz & 1) * 384;
  const int tid = threadIdx.x;
  const int w = tid >> 6, lane = tid & 63;

  const int srow = w * 16 + (lane >> 2);
  const int sk8 = ((lane & 3) ^ ((lane >> 3) & 3)) * 8;
  const int rby = ((lane >> 4) ^ ((lane >> 1) & 3)) * 16;
  const int rrow = lane & 15;

  const int pr = tid >> 2, pc = tid & 3;  // P-compute: row, 8-j chunk
  const int ppos = pc ^ ((pr >> 1) & 3);  // swizzled write position

  const _Float16* hTb = hT16 + (size_t)b * DF * SS;

  f32x4 acc[8][3];
#pragma unroll
  for (int mi = 0; mi < 8; ++mi)
#pragma unroll
    for (int ni = 0; ni < 3; ++ni) acc[mi][ni] = (f32x4)(0.f);

#define STGB2(s, kt, q)                                                    \
  gload16(&hTb[((size_t)(d0 + (q) * 128 + srow)) * SS + (kt) * 32 + sk8],  \
          smem + (s) * 32768 + 8192 + (q) * 8192 + w * 1024)

  // PCALC: factorized P, all-f16, no transcendental
#define PCALC(sjch, c1h, c2h, mbit)                                        \
  ((c2h) < (_Float16)0.f                                                   \
       ? (_Float16)0.0009765625f                                           \
       : (!(mbit) ? (_Float16)0.f                                          \
                  : ((_Float16)(sih + (sjch)) >= (_Float16)0.f             \
                         ? (_Float16)(e1h * (c1h))                         \
                         : (_Float16)(e2h * (c2h)))))

#define COMPUTE_P(kt, slot)                                                  \
  {                                                                          \
    const unsigned mw =                                                      \
        *(const unsigned*)(smem + 139264 + pr * 144 + (kt) * 4);             \
    const unsigned mb = (mw >> (pc * 8)) & 0xffu;                            \
    const char* sqb = smem + 131072 + (kt) * 256 + pc * 64;                  \
    const f16x8 q0 = *(const f16x8*)(sqb);                                   \
    const f16x8 q1 = *(const f16x8*)(sqb + 16);                              \
    const f16x8 q2 = *(const f16x8*)(sqb + 32);                              \
    const f16x8 q3 = *(const f16x8*)(sqb + 48);                              \
    f16x8 ph;                                                                \
    ph[0] = PCALC(q0[0], q0[1], q0[2], (mb & 1u));                           \
    ph[1] = PCALC(q0[4], q0[5], q0[6], ((mb >> 1) & 1u));                    \
    ph[2] = PCALC(q1[0], q1[1], q1[2], ((mb >> 2) & 1u));                    \
    ph[3] = PCALC(q1[4], q1[5], q1[6], ((mb >> 3) & 1u));                    \
    ph[4] = PCALC(q2[0], q2[1], q2[2], ((mb >> 4) & 1u));                    \
    ph[5] = PCALC(q2[4], q2[5], q2[6], ((mb >> 5) & 1u));                    \
    ph[6] = PCALC(q3[0], q3[1], q3[2], ((mb >> 6) & 1u));                    \
    ph[7] = PCALC(q3[4], q3[5], q3[6], ((mb >> 7) & 1u));                    \
    *(f16x8*)(smem + (slot) * 32768 + pr * 64 + ppos * 16) = ph;             \
  }

  // ---- prologue ----
  const unsigned char* bmb = bmk + ((size_t)b << 17) + ((size_t)i0 << 7);
  const uint4 mg0 = *(const uint4*)(bmb + tid * 32);
  const uint4 mg1 = *(const uint4*)(bmb + tid * 32 + 16);
  // sq: 1024 j x 8B = 8KB; all 512 threads load 16B each
  gload16((const char*)(sq_g + ((size_t)b << 10)) + tid * 16,
          smem + 131072 + w * 1024);
  const float siv =
      psi2[(b << 10) + i0 + pr] + psi2[16384 + (b << 10) + i0 + pr];
  const _Float16 sih = (_Float16)siv;
  const _Float16 e1h = (_Float16)__expf(siv);
  const _Float16 e2h = (_Float16)__expf(0.2f * siv);
  const int NT = SS / 32;  // 32
  STGB2(0, 0, 0); STGB2(0, 0, 1); STGB2(0, 0, 2);
  STGB2(1, 1, 0); STGB2(1, 1, 1); STGB2(1, 1, 2);
  asm volatile("s_waitcnt vmcnt(0)" ::: "memory");
  *(uint4*)(smem + 139264 + pr * 144 + pc * 32) = mg0;
  *(uint4*)(smem + 139264 + pr * 144 + pc * 32 + 16) = mg1;
  asm volatile("s_waitcnt lgkmcnt(0)" ::: "memory");
  asm volatile("s_barrier" ::: "memory");
  COMPUTE_P(0, 0);
  asm volatile("s_waitcnt lgkmcnt(0)" ::: "memory");
  asm volatile("s_barrier" ::: "memory");

  for (int t = 0; t < NT; ++t) {
    const char* Ab = smem + (t & 3) * 32768;
    const char* Bb = Ab + 8192;
    f16x8 bfr[3], afr[8];
#pragma unroll
    for (int ni = 0; ni < 3; ++ni)
      bfr[ni] = *(const f16x8*)(Bb + (w * 48 + ni * 16 + rrow) * 64 + rby);
#pragma unroll
    for (int mi = 0; mi < 8; ++mi)
      afr[mi] = *(const f16x8*)(Ab + (mi * 16 + rrow) * 64 + rby);
    if (t + 1 < NT) COMPUTE_P(t + 1, (t + 1) & 3);
    if (t + 2 < NT) {
      const int s2 = (t + 2) & 3;
      STGB2(s2, t + 2, 0);
      STGB2(s2, t + 2, 1);
      STGB2(s2, t + 2, 2);
    }
    if (t < NT - 2)
      asm volatile("s_waitcnt vmcnt(3) lgkmcnt(0)" ::: "memory");
    else
      asm volatile("s_waitcnt vmcnt(0) lgkmcnt(0)" ::: "memory");
    asm volatile("s_barrier" ::: "memory");
    __builtin_amdgcn_s_setprio(1);
#pragma unroll
    for (int mi = 0; mi < 8; ++mi)
#pragma unroll
      for (int ni = 0; ni < 3; ++ni)
        acc[mi][ni] = __builtin_amdgcn_mfma_f32_16x16x32_f16(
            afr[mi], bfr[ni], acc[mi][ni], 0, 0, 0);
    __builtin_amdgcn_s_setprio(0);
  }
#undef STGB2
#undef COMPUTE_P
#undef PCALC

  const int cg = lane >> 4, cr = lane & 15;
#pragma unroll
  for (int mi = 0; mi < 8; ++mi) {
#pragma unroll
    for (int ni = 0; ni < 3; ++ni) {
      const int d = d0 + w * 48 + ni * 16 + cr;
      const int row0 = i0 + mi * 16 + cg * 4;
#pragma unroll
      for (int r = 0; r < 4; ++r) {
        float v = acc[mi][ni][r];
        size_t o = ((size_t)b * SS + row0 + r) * DF + d;
        outl[o] = v;
        if (writeX) X16n[o] = (_Float16)v;
      }
    }
  }
}

// ---------------------------------------------------------------------------
// colsum (refj-free, reads partials directly): per column j accumulate
//   S1 = sum_{masked i, si+sjc>=0} e^{si}, S2 = sum_{masked i, <0} e^{0.2 si}
// ---------------------------------------------------------------------------
__global__ __launch_bounds__(256) void colsum_k(
    const unsigned char* __restrict__ bm, const float* __restrict__ psi2,
    const float* __restrict__ psj2, const float* __restrict__ Abp,
    float* __restrict__ pden1, float* __restrict__ pden2) {
  const int g = blockIdx.x;  // 0..31
  const int b = blockIdx.y;  // 0..15
  const int t = threadIdx.x;
  const int jb = t & 127;
  const int half = t >> 7;
  const int row0 = (g << 5) + (half << 4);
  const float ab = Abp[0];
  __shared__ float s_si[32], s_e1[32], s_e2[32];
  if (t < 32) {
    const int ridx = (b << 10) + (g << 5) + t;
    const float v = psi2[ridx] + psi2[16384 + ridx];
    s_si[t] = v;
    s_e1[t] = __expf(v);
    s_e2[t] = __expf(0.2f * v);
  }
  __syncthreads();
  float sc[8];
  {
    const int jidx = (b << 10) + jb * 8;
    float4 a0 = *(const float4*)&psj2[jidx];
    float4 a1 = *(const float4*)&psj2[jidx + 4];
    float4 b0 = *(const float4*)&psj2[16384 + jidx];
    float4 b1 = *(const float4*)&psj2[16384 + jidx + 4];
    sc[0] = a0.x + b0.x + ab; sc[1] = a0.y + b0.y + ab;
    sc[2] = a0.z + b0.z + ab; sc[3] = a0.w + b0.w + ab;
    sc[4] = a1.x + b1.x + ab; sc[5] = a1.y + b1.y + ab;
    sc[6] = a1.z + b1.z + ab; sc[7] = a1.w + b1.w + ab;
  }
  float d1[8] = {0.f, 0.f, 0.f, 0.f, 0.f, 0.f, 0.f, 0.f};
  float d2[8] = {0.f, 0.f, 0.f, 0.f, 0.f, 0.f, 0.f, 0.f};
  const unsigned char* bp = bm + ((size_t)b << 17) + ((size_t)row0 << 7) + jb;
#pragma unroll 4
  for (int r = 0; r < 16; ++r) {
    const unsigned m = bp[(size_t)r << 7];
    const int ri = (half << 4) + r;
    const float siv = s_si[ri], e1v = s_e1[ri], e2v = s_e2[ri];
#pragma unroll
    for (int k = 0; k < 8; ++k) {
      if ((m >> k) & 1) {
        if (siv + sc[k] >= 0.f)
          d1[k] += e1v;
        else
          d2[k] += e2v;
      }
    }
  }
  const size_t o = ((size_t)(g * 2 + half)) * 16384 + (b << 10) + jb * 8;
  *(float4*)&pden1[o] = *(float4*)&d1[0];
  *(float4*)&pden1[o + 4] = *(float4*)&d1[4];
  *(float4*)&pden2[o] = *(float4*)&d2[0];
  *(float4*)&pden2[o + 4] = *(float4*)&d2[4];
}

// ---------------------------------------------------------------------------
// colfin (refj-free): den = e^{sjc}*S1 + e^{0.2sjc}*S2; pack per j (8B):
//   [sjc, c1, c2, 0] halves, c1 = e^{sjc}/den, c2 = e^{0.2sjc}/den;
//   all-masked column -> c2 = -1/1024 sentinel.
// ---------------------------------------------------------------------------
__global__ __launch_bounds__(256) void colfin_k(
    const float* __restrict__ pden1, const float* __restrict__ pden2,
    const float* __restrict__ psj2, const float* __restrict__ Abp,
    uint2* __restrict__ sq) {
  const int idx = blockIdx.x * 256 + threadIdx.x;  // b*1024 + j
  float S1 = 0.f, S2 = 0.f;
#pragma unroll
  for (int c = 0; c < 64; ++c) {
    S1 += pden1[(size_t)c * 16384 + idx];
    S2 += pden2[(size_t)c * 16384 + idx];
  }
  const float sj = psj2[idx] + psj2[16384 + idx] + Abp[0];
  const float A1 = __expf(sj);
  const float A2 = __expf(0.2f * sj);
  const float den = A1 * S1 + A2 * S2;
  _Float16 sjh = (_Float16)sj;
  _Float16 c1h, c2h;
  if (den > 0.f) {
    c1h = (_Float16)(A1 / den);
    c2h = (_Float16)(A2 / den);
  } else {
    c1h = (_Float16)0.f;
    c2h = (_Float16)(-0.0009765625f);
  }
  unsigned short u0, u1, u2;
  __builtin_memcpy(&u0, &sjh, 2);
  __builtin_memcpy(&u1, &c1h, 2);
  __builtin_memcpy(&u2, &c2h, 2);
  uint2 outw;
  outw.x = (unsigned)u0 | ((unsigned)u1 << 16);
  outw.y = (unsigned)u2;
  sq[idx] = outw;
}

// ---------------------------------------------------------------------------
extern "C" void kernel_launch(void* const* d_in, const int* in_sizes, int n_in,
                              void* d_out, int out_size, void* d_ws,
                              size_t ws_size, hipStream_t stream) {
  const float* X0 = (const float*)d_in[0];
  const int* mask = (const int*)d_in[1];
  const float* W = (const float*)d_in[2];
  const float* Wb = (const float*)d_in[3];
  const float* A = (const float*)d_in[4];
  const float* Ab = (const float*)d_in[5];
  float* out = (float*)d_out;

  const size_t BSD = (size_t)NBATCH * SS * DF;  // 12,582,912 elems
  const size_t BSS = (size_t)NBATCH * SS * SS;  // 16,777,216 elems
  const size_t BS = (size_t)NBATCH * SS;        // 16,384 elems

  char* p = (char*)d_ws;
  _Float16* X16 = (_Float16*)p;   p += BSD * 2;                   // 24 MB
  _Float16* hT16 = (_Float16*)p;  p += BSD * 2;                   // 24 MB
  _Float16* W16 = (_Float16*)p;   p += (size_t)2 * DF * DF * 2;   // 2.25 MB
  unsigned char* bmk = (unsigned char*)p; p += BSS / 8;           // 2 MB
  float* psi2 = (float*)p;  p += 2 * BS * 4;   // 128 KB
  float* psj2 = (float*)p;  p += 2 * BS * 4;   // 128 KB
  float* pden1 = (float*)p; p += 64 * BS * 4;  // 4 MB
  float* pden2 = (float*)p; p += 64 * BS * 4;  // 4 MB
  uint2* sq_g = (uint2*)p;  p += BS * 8;       // 8B/j packed (sjc,c1,c2)

  pre_k<<<21632, 256, 0, stream>>>(X0, X16, W, W16, mask, bmk);

  for (int l = 0; l < 2; ++l) {
    gemm1_k<<<256, 512, 0, stream>>>(X16, W16 + (size_t)l * DF * DF,
                                     Wb + (size_t)l * DF,
                                     A + (size_t)l * 2 * DF, hT16, psi2, psj2);
    colsum_k<<<dim3(32, 16), 256, 0, stream>>>(bmk, psi2, psj2, Ab + l, pden1,
                                               pden2);
    colfin_k<<<64, 256, 0, stream>>>(pden1, pden2, psj2, Ab + l, sq_g);
    gemm2_k<<<256, 512, 0, stream>>>(bmk, psi2, sq_g, hT16,
                                     out + (size_t)l * BSD, X16,
                                     (l == 0) ? 1 : 0);
  }
}